// Round 9
// baseline (394.230 us; speedup 1.0000x reference)
//
#include <hip/hip_runtime.h>
#include <stdint.h>

#define NUM_KP 17
#define BATCH  32
#define HDIM   256
#define WDIM   256
#define NCH    (BATCH * NUM_KP)     // 544 channels
#define MAXP   30
#define QBLKS  4                    // quarter-channels -> 2176 blocks in kernel 1
#define K1THREADS 256               // 4 waves/block

// 12-bit score quantization: q = (float_bits >> 13) - QB, clamped [1, 4095].
// Scores in (0.1, 1] -> q in [613, 4095]; per quarter ~16 in top bin -> survivors ~46.
#define NBINS  4096
#define QB     125953               // (0x3F800000 >> 13) - 4095

// ws: 2176 blocks x 30 keys x 8 B = 522 KB of partial top-30 keys.
#define WS_REQUIRED ((size_t)NCH * QBLKS * MAXP * 8)

__device__ __forceinline__ unsigned quant12(float v) {
    int b = (int)(__float_as_uint(v) >> 13) - QB;
    b = b < 1 ? 1 : (b > NBINS - 1 ? NBINS - 1 : b);
    return (unsigned)b;
}

// ---- Kernel 1: quarter-channel NMS, two-pass (histogram then survivor
// recompute), parallel rank-order partial top-30 -> ws keys.
// LDS ~= 8K hist + 1K gsum + 2K ref + ctl ~= 11.3 KB; launch_bounds(256,8)
// -> 8 blocks/CU (32 waves = full occupancy); no candidate buffer at all. ----
__global__ __launch_bounds__(K1THREADS, 8)
void pose_part_kernel(const float* __restrict__ heat, unsigned long long* __restrict__ part) {
    __shared__ unsigned s_hist[NBINS / 2];       // packed u16 pairs
    __shared__ int s_gsum[256];                  // each = sum of 16 bins
    __shared__ unsigned long long s_ref[256];    // exact survivor keys
    __shared__ int s_nref, s_tau;

    const int tid  = threadIdx.x;
    const int chan = blockIdx.x >> 2;
    const int qtr  = blockIdx.x & 3;
    const int wave = tid >> 6;
    const int lane = tid & 63;
    const float NEGINF = -__builtin_inff();
    const float* __restrict__ cp = heat + (size_t)chan * (HDIM * WDIM);

    for (int i = tid; i < NBINS / 2; i += K1THREADS) s_hist[i] = 0;
    if (tid == 0) s_nref = 0;
    __syncthreads();

    const int r0 = (qtr << 6) + (wave << 4);     // this wave owns rows r0..r0+15
    const float* colp = cp + (lane << 2);
    const float4 NEG4 = make_float4(NEGINF, NEGINF, NEGINF, NEGINF);

    auto LD = [&](int r) -> float4 {
        return (r >= 0 && r < HDIM) ? *(const float4*)(colp + (r << 8)) : NEG4;
    };
    // 3x3-NMS one row; calls emit(value, pixel_idx) for each peak > 0.1
    auto process = [&](const float4& up, const float4& md, const float4& dn, int r,
                       auto&& emit) {
        float vm0 = fmaxf(up.x, fmaxf(md.x, dn.x));
        float vm1 = fmaxf(up.y, fmaxf(md.y, dn.y));
        float vm2 = fmaxf(up.z, fmaxf(md.z, dn.z));
        float vm3 = fmaxf(up.w, fmaxf(md.w, dn.w));
        float left  = __shfl_up(vm3, 1);   if (lane == 0)  left  = NEGINF;
        float right = __shfl_down(vm0, 1); if (lane == 63) right = NEGINF;
        float h0 = fmaxf(left, fmaxf(vm0, vm1));
        float h1 = fmaxf(vm0, fmaxf(vm1, vm2));
        float h2 = fmaxf(vm1, fmaxf(vm2, vm3));
        float h3 = fmaxf(vm2, fmaxf(vm3, right));
        const int base = (r << 8) | (lane << 2);
        if (md.x > 0.1f && md.x == h0) emit(md.x, base + 0);
        if (md.y > 0.1f && md.y == h1) emit(md.y, base + 1);
        if (md.z > 0.1f && md.z == h2) emit(md.z, base + 2);
        if (md.w > 0.1f && md.w == h3) emit(md.w, base + 3);
    };
    // full 16-row sweep, groups of 4 with 1-group prefetch
    auto sweep = [&](auto&& emit) {
        float4 rm   = LD(r0 - 1);
        float4 cur0 = LD(r0 + 0), cur1 = LD(r0 + 1), cur2 = LD(r0 + 2), cur3 = LD(r0 + 3);
        #pragma unroll
        for (int g = 0; g < 4; ++g) {
            const int rb = r0 + (g << 2);
            float4 n0, n1, n2, n3;
            if (g < 3) { n0 = LD(rb + 4); n1 = LD(rb + 5); n2 = LD(rb + 6); n3 = LD(rb + 7); }
            else       { n0 = LD(rb + 4); n1 = NEG4; n2 = NEG4; n3 = NEG4; }
            process(rm,   cur0, cur1, rb + 0, emit);
            process(cur0, cur1, cur2, rb + 1, emit);
            process(cur1, cur2, cur3, rb + 2, emit);
            process(cur2, cur3, n0,   rb + 3, emit);
            rm = cur3; cur0 = n0; cur1 = n1; cur2 = n2; cur3 = n3;
        }
    };

    // ---- Pass A: histogram only (fire-and-forget packed u16 atomics) ----
    sweep([&](float v, int pidx) {
        unsigned q = quant12(v);
        atomicAdd(&s_hist[q >> 1], 1u << ((q & 1) << 4));
        (void)pidx;
    });
    __syncthreads();

    // ---- Phase 2: parallel suffix scan -> bin threshold tau (rank MAXP) ----
    {
        int s = 0;
        #pragma unroll
        for (int j = 0; j < 8; ++j) {
            unsigned w = s_hist[tid * 8 + j];
            s += (int)(w & 0xFFFFu) + (int)(w >> 16);
        }
        s_gsum[tid] = s;
    }
    __syncthreads();
    if (wave == 0) {            // one-wave suffix scan over 256 group sums
        int u0 = s_gsum[(lane << 2) + 0], u1 = s_gsum[(lane << 2) + 1];
        int u2 = s_gsum[(lane << 2) + 2], u3 = s_gsum[(lane << 2) + 3];
        int t = u0 + u1 + u2 + u3;
        int R = t;
        #pragma unroll
        for (int off = 1; off < 64; off <<= 1) {
            int v = __shfl_down(R, off);
            if (lane + off < 64) R += v;
        }
        int E = R - t;                       // sum over lanes > me
        int sg3 = u3 + E, sg2 = u2 + sg3, sg1 = u1 + sg2, sg0 = u0 + sg1;
        unsigned long long mask = __ballot(sg0 >= MAXP);
        if (mask == 0ull) {
            if (lane == 0) s_tau = 0;        // fewer than MAXP total -> collect all
        } else {
            int hi = 63 - __builtin_clzll(mask);
            if (lane == hi) {
                int k, above;
                if      (sg3 >= MAXP) { k = 3; above = E;   }
                else if (sg2 >= MAXP) { k = 2; above = sg3; }
                else if (sg1 >= MAXP) { k = 1; above = sg2; }
                else                  { k = 0; above = sg1; }
                int g = (lane << 2) + k;
                int cum = above, tau = 0;
                for (int b = (g << 4) + 15; b >= (g << 4); --b) {
                    cum += (int)((s_hist[b >> 1] >> ((b & 1) << 4)) & 0xFFFFu);
                    if (cum >= MAXP) { tau = b; break; }
                }
                s_tau = tau;
            }
        }
    }
    __syncthreads();

    // ---- Pass B: recompute NMS (L1/L2-hot), keep survivors q >= tau (~46);
    //      exact score bits come straight from registers. ----
    const unsigned tau = (unsigned)s_tau;
    sweep([&](float v, int pidx) {
        if (quant12(v) >= tau) {
            int pos = atomicAdd(&s_nref, 1);
            if (pos < 256) {
                // key: higher score wins; tie -> smaller idx (matches lax.top_k)
                s_ref[pos] = ((unsigned long long)__float_as_uint(v) << 32)
                           | (unsigned)(~(unsigned)pidx);
            }
        }
    });
    __syncthreads();

    // ---- Phase 4: parallel rank-order scatter of partial top-30 ----
    const int nref = s_nref < 256 ? s_nref : 256;
    unsigned long long* pk = part + (size_t)blockIdx.x * MAXP;
    const int nv = nref < MAXP ? nref : MAXP;
    if (tid >= nv && tid < MAXP) pk[tid] = 0ull;     // empty slots (disjoint from ranks)
    if (tid < nref) {
        unsigned long long k = s_ref[tid];
        int rank = 0;
        for (int j = 0; j < nref; ++j) rank += (s_ref[j] > k) ? 1 : 0;
        if (rank < MAXP) pk[rank] = k;               // ranks unique (keys distinct)
    }
}

// ---- Kernel 2: merge 4 x 30 partial keys per channel by parallel rank ----
__global__ __launch_bounds__(128)
void pose_merge_kernel(const unsigned long long* __restrict__ part,
                       float* __restrict__ out, int out_size) {
    __shared__ unsigned long long s_k[128];
    const int chan = blockIdx.x;
    const int tid  = threadIdx.x;
    const int NK   = QBLKS * MAXP;                   // 120
    const float NEGINF = -__builtin_inff();
    const unsigned long long* pk = part + (size_t)chan * NK;

    s_k[tid] = (tid < NK) ? pk[tid] : 0ull;
    __syncthreads();

    if (tid < NK) {
        unsigned long long k = s_k[tid];
        int rank = 0;
        for (int j = 0; j < NK; ++j) {
            unsigned long long o = s_k[j];
            rank += (o > k || (o == k && j < tid)) ? 1 : 0;   // positional tie-break (zeros)
        }
        if (rank < MAXP) {
            float sc, vld; unsigned idx;
            if (k != 0ull) {
                sc  = __uint_as_float((unsigned)(k >> 32));
                idx = (~(unsigned)k) & 0xFFFFu;
                vld = 1.0f;
            } else { sc = NEGINF; idx = 0u; vld = 0.0f; }
            int x = (int)(idx & 255), y = (int)(idx >> 8);
            long long cb = ((long long)chan * MAXP + rank) * 2;
            if (cb + 1 < out_size) {
                out[cb]     = (float)(x * 4);        // (x, y) * STRIDE
                out[cb + 1] = (float)(y * 4);
            }
            long long so = (long long)NCH * MAXP * 2 + (long long)chan * MAXP + rank;
            if (so < out_size) out[so] = sc;
            long long vo = (long long)NCH * MAXP * 3 + (long long)chan * MAXP + rank;
            if (vo < out_size) out[vo] = vld;
        }
    }
}

extern "C" void kernel_launch(void* const* d_in, const int* in_sizes, int n_in,
                              void* d_out, int out_size, void* d_ws, size_t ws_size,
                              hipStream_t stream) {
    const float* heat = (const float*)d_in[0];
    float* out = (float*)d_out;
    unsigned long long* part = (unsigned long long*)d_ws;
    hipLaunchKernelGGL(pose_part_kernel, dim3(NCH * QBLKS), dim3(K1THREADS), 0, stream,
                       heat, part);
    hipLaunchKernelGGL(pose_merge_kernel, dim3(NCH), dim3(128), 0, stream,
                       part, out, out_size);
}